// Round 1
// baseline (411.362 us; speedup 1.0000x reference)
//
#include <hip/hip_runtime.h>
#include <hip/hip_bf16.h>

typedef unsigned short u16;
typedef __attribute__((ext_vector_type(8))) short bf16x8;
typedef __attribute__((ext_vector_type(4))) float f32x4;

#define MFMA(a, b, c) __builtin_amdgcn_mfma_f32_16x16x32_bf16(a, b, c, 0, 0, 0)

__device__ inline u16 f2bf(float f) {
    union { __hip_bfloat16 b; u16 u; } cv;
    cv.b = __float2bfloat16(f);
    return cv.u;
}

__device__ inline f32x4 zero4() {
    f32x4 v; v[0] = 0.f; v[1] = 0.f; v[2] = 0.f; v[3] = 0.f; return v;
}

// ---------------- fp32 -> bf16 elementwise (n = 4M, 4 elems/thread) ----------------
__global__ __launch_bounds__(256) void cvt_kernel(const float* __restrict__ in, u16* __restrict__ out) {
    int i = (blockIdx.x * 256 + threadIdx.x) * 4;
    float4 v = *(const float4*)(in + i);
    u16 o[4] = { f2bf(v.x), f2bf(v.y), f2bf(v.z), f2bf(v.w) };
    *(uint2*)(out + i) = *(const uint2*)o;
}

// ---------------- per-head weight transpose fp32 -> bf16 ----------------
// src slice per h: (R, C) row-major. element (i, j) -> dst[h*ho + j*1024 + i]
// wq/wk/wv: R=1024(m), C=64(d), ho=64*1024  => Wt[(h*64+d)*1024 + m]
// wo:       R=64(v),  C=1024(m), ho=64      => Wot[m*1024 + h*64 + v]
__global__ __launch_bounds__(256) void wtrans_kernel(const float* __restrict__ src, u16* __restrict__ dst,
                                                     int R, int C, int ho) {
    __shared__ float tile[64][65];
    int h = blockIdx.z;
    int r0 = blockIdx.x * 64, c0 = blockIdx.y * 64;
    const float* s = src + (size_t)h * R * C;
    int tid = threadIdx.x;
#pragma unroll
    for (int k = 0; k < 16; k++) {
        int idx = tid + k * 256;
        int i = idx >> 6, j = idx & 63;
        tile[i][j] = s[(size_t)(r0 + i) * C + (c0 + j)];
    }
    __syncthreads();
    u16* d = dst + (size_t)h * ho;
#pragma unroll
    for (int k = 0; k < 16; k++) {
        int idx = tid + k * 256;
        int j = idx >> 6, i = idx & 63;
        d[(size_t)(c0 + j) * 1024 + (r0 + i)] = f2bf(tile[i][j]);
    }
}

// ---------------- V (B,T,H,V) -> Vt (B,H,V,T), bf16 ----------------
__global__ __launch_bounds__(256) void vtrans_kernel(const u16* __restrict__ Vp, u16* __restrict__ Vt) {
    __shared__ u16 tile[64][72];
    int t0 = blockIdx.x * 64, h = blockIdx.y, b = blockIdx.z;
    int tid = threadIdx.x;
#pragma unroll
    for (int k = 0; k < 16; k++) {
        int idx = tid + k * 256;
        int tl = idx >> 6, vl = idx & 63;
        tile[tl][vl] = Vp[(size_t)(b * 1024 + t0 + tl) * 1024 + h * 64 + vl];
    }
    __syncthreads();
#pragma unroll
    for (int k = 0; k < 16; k++) {
        int idx = tid + k * 256;
        int vl = idx >> 6, tl = idx & 63;
        Vt[((size_t)(b * 16 + h) * 64 + vl) * 1024 + t0 + tl] = tile[tl][vl];
    }
}

// ---------------- bf16 MFMA GEMM: C(4096x1024) = A(4096x1024) @ Bt(1024x1024)^T ----------------
// Bt is stored (n, k) row-major. 128x128 tile, 256 threads, 2x2 waves, 4x4 MFMA tiles each.
// Cf != nullptr -> fp32 out with (1 - qmask[row]) scale; else bf16 out to Cb.
__global__ __launch_bounds__(256) void gemm_kernel(const u16* __restrict__ A, const u16* __restrict__ Bt,
                                                   u16* __restrict__ Cb, float* __restrict__ Cf,
                                                   const float* __restrict__ qmask) {
    __shared__ __align__(16) u16 As[128 * 32];
    __shared__ __align__(16) u16 Bs[128 * 32];
    int tid = threadIdx.x;
    int m0 = blockIdx.x * 128, n0 = blockIdx.y * 128;
    int w = tid >> 6, lane = tid & 63, quad = lane >> 4, c = lane & 15;
    int mw = (w & 1) * 64, nw = (w >> 1) * 64;
    f32x4 acc[4][4];
#pragma unroll
    for (int i = 0; i < 4; i++)
#pragma unroll
        for (int j = 0; j < 4; j++) acc[i][j] = zero4();

    for (int k0 = 0; k0 < 1024; k0 += 32) {
        __syncthreads();
#pragma unroll
        for (int s = 0; s < 2; s++) {
            int ch = tid + s * 256;
            int r = ch >> 2, cc = (ch & 3) * 8;
            *(uint4*)&As[ch * 8] = *(const uint4*)&A[(size_t)(m0 + r) * 1024 + k0 + cc];
            *(uint4*)&Bs[ch * 8] = *(const uint4*)&Bt[(size_t)(n0 + r) * 1024 + k0 + cc];
        }
        __syncthreads();
        bf16x8 af[4], bfr[4];
#pragma unroll
        for (int i = 0; i < 4; i++) af[i] = *(const bf16x8*)&As[(mw + i * 16 + c) * 32 + quad * 8];
#pragma unroll
        for (int j = 0; j < 4; j++) bfr[j] = *(const bf16x8*)&Bs[(nw + j * 16 + c) * 32 + quad * 8];
#pragma unroll
        for (int i = 0; i < 4; i++)
#pragma unroll
            for (int j = 0; j < 4; j++) acc[i][j] = MFMA(af[i], bfr[j], acc[i][j]);
    }
#pragma unroll
    for (int i = 0; i < 4; i++) {
#pragma unroll
        for (int r = 0; r < 4; r++) {
            int row = m0 + mw + i * 16 + quad * 4 + r;
            float scale = (Cf != nullptr) ? (1.0f - qmask[row]) : 1.0f;
#pragma unroll
            for (int j = 0; j < 4; j++) {
                int col = n0 + nw + j * 16 + c;
                float v = acc[i][j][r];
                if (Cf != nullptr) Cf[(size_t)row * 1024 + col] = v * scale;
                else               Cb[(size_t)row * 1024 + col] = f2bf(v);
            }
        }
    }
}

// ---------------- flash attention + column marginals ----------------
// grid (qb=16, h=16, b=4), 256 thr. wave w -> q rows [qb*64+w*16, +16). C/D layout:
// row = quad*4+reg, col = lane&15. m_run init 0 == reference max(rowmax, 0).
__global__ __launch_bounds__(256) void attn_kernel(const u16* __restrict__ Qp, const u16* __restrict__ Kp,
                                                   const u16* __restrict__ Vt, u16* __restrict__ Pre,
                                                   float* __restrict__ marg) {
    __shared__ float colbuf[1024];
    __shared__ __align__(16) u16 plds[4][16 * 40];
    int tid = threadIdx.x;
    int qb = blockIdx.x, h = blockIdx.y, b = blockIdx.z;
    for (int i = tid; i < 1024; i += 256) colbuf[i] = 0.f;
    __syncthreads();

    int w = tid >> 6, lane = tid & 63, quad = lane >> 4, c = lane & 15;
    int q0 = qb * 64 + w * 16;
    const u16* qrow = Qp + (size_t)(b * 1024 + q0 + c) * 1024 + h * 64;
    bf16x8 aq0 = *(const bf16x8*)(qrow + quad * 8);
    bf16x8 aq1 = *(const bf16x8*)(qrow + 32 + quad * 8);
    f32x4 o[4];
#pragma unroll
    for (int i = 0; i < 4; i++) o[i] = zero4();
    float m_run[4] = {0.f, 0.f, 0.f, 0.f};
    float l_run[4] = {0.f, 0.f, 0.f, 0.f};
    const float sc = 0.125f * 1.4426950408889634f;  // kscale * log2(e): exp2 domain
    const float NEG = -3.0e38f;
    int tend = q0 + 16;
    u16* pl = plds[w];
    const u16* kbase = Kp + (size_t)b * 1024 * 1024 + h * 64;
    const u16* vbase = Vt + (size_t)(b * 16 + h) * 64 * 1024;

    for (int t0 = 0; t0 < tend; t0 += 32) {
        f32x4 s0 = zero4(), s1 = zero4();
        {
            const u16* k0p = kbase + (size_t)(t0 + c) * 1024 + quad * 8;
            bf16x8 b0 = *(const bf16x8*)(k0p);
            bf16x8 b1 = *(const bf16x8*)(k0p + 32);
            s0 = MFMA(aq0, b0, s0); s0 = MFMA(aq1, b1, s0);
            const u16* k1p = kbase + (size_t)(t0 + 16 + c) * 1024 + quad * 8;
            bf16x8 b2 = *(const bf16x8*)(k1p);
            bf16x8 b3 = *(const bf16x8*)(k1p + 32);
            s1 = MFMA(aq0, b2, s1); s1 = MFMA(aq1, b3, s1);
        }
        float p0[4], p1[4];
#pragma unroll
        for (int r = 0; r < 4; r++) {
            int qg = q0 + quad * 4 + r;
            float v0 = (t0 + c <= qg) ? s0[r] * sc : NEG;
            float v1 = (t0 + 16 + c <= qg) ? s1[r] * sc : NEG;
            float mx = fmaxf(v0, v1);
#pragma unroll
            for (int d = 1; d < 16; d <<= 1) mx = fmaxf(mx, __shfl_xor(mx, d));
            float mnew = fmaxf(m_run[r], mx);
            float alpha = exp2f(m_run[r] - mnew);
            float e0 = exp2f(v0 - mnew);
            float e1 = exp2f(v1 - mnew);
            float rs = e0 + e1;
#pragma unroll
            for (int d = 1; d < 16; d <<= 1) rs += __shfl_xor(rs, d);
            l_run[r] = l_run[r] * alpha + rs;
            m_run[r] = mnew;
            o[0][r] *= alpha; o[1][r] *= alpha; o[2][r] *= alpha; o[3][r] *= alpha;
            p0[r] = e0; p1[r] = e1;
        }
        // P: C-layout -> LDS (row-padded to 40 for 16B-aligned conflict-light reads) -> A-layout
#pragma unroll
        for (int r = 0; r < 4; r++) {
            pl[(quad * 4 + r) * 40 + c]      = f2bf(p0[r]);
            pl[(quad * 4 + r) * 40 + 16 + c] = f2bf(p1[r]);
        }
        asm volatile("s_waitcnt lgkmcnt(0)" ::: "memory");  // in-wave LDS RAW fence
        bf16x8 ap = *(const bf16x8*)&pl[c * 40 + quad * 8];
#pragma unroll
        for (int vt = 0; vt < 4; vt++) {
            bf16x8 bv = *(const bf16x8*)(vbase + (size_t)(vt * 16 + c) * 1024 + t0 + quad * 8);
            o[vt] = MFMA(ap, bv, o[vt]);
        }
    }

    float invl[4];
#pragma unroll
    for (int r = 0; r < 4; r++) invl[r] = 1.0f / l_run[r];
    // write Pre (B,Q,H,V) bf16
#pragma unroll
    for (int vt = 0; vt < 4; vt++)
#pragma unroll
        for (int r = 0; r < 4; r++) {
            size_t row = (size_t)(b * 1024 + q0 + quad * 4 + r);
            Pre[row * 1024 + h * 64 + vt * 16 + c] = f2bf(o[vt][r] * invl[r]);
        }

    // phase 2: column marginals  sum_q att[q,t] * (q+1)
    float wr[4];
#pragma unroll
    for (int r = 0; r < 4; r++) wr[r] = (float)(q0 + quad * 4 + r + 1) * invl[r];
    for (int t0 = 0; t0 < tend; t0 += 32) {
        f32x4 s0 = zero4(), s1 = zero4();
        {
            const u16* k0p = kbase + (size_t)(t0 + c) * 1024 + quad * 8;
            bf16x8 b0 = *(const bf16x8*)(k0p);
            bf16x8 b1 = *(const bf16x8*)(k0p + 32);
            s0 = MFMA(aq0, b0, s0); s0 = MFMA(aq1, b1, s0);
            const u16* k1p = kbase + (size_t)(t0 + 16 + c) * 1024 + quad * 8;
            bf16x8 b2 = *(const bf16x8*)(k1p);
            bf16x8 b3 = *(const bf16x8*)(k1p + 32);
            s1 = MFMA(aq0, b2, s1); s1 = MFMA(aq1, b3, s1);
        }
        float cs0 = 0.f, cs1 = 0.f;
#pragma unroll
        for (int r = 0; r < 4; r++) {
            int qg = q0 + quad * 4 + r;
            if (t0 + c <= qg)      cs0 += exp2f(s0[r] * sc - m_run[r]) * wr[r];
            if (t0 + 16 + c <= qg) cs1 += exp2f(s1[r] * sc - m_run[r]) * wr[r];
        }
        cs0 += __shfl_xor(cs0, 16); cs0 += __shfl_xor(cs0, 32);
        cs1 += __shfl_xor(cs1, 16); cs1 += __shfl_xor(cs1, 32);
        if (lane < 16)      atomicAdd(&colbuf[t0 + lane], cs0);
        else if (lane < 32) atomicAdd(&colbuf[t0 + lane], cs1);  // t0+16+(lane&15) == t0+lane
    }
    __syncthreads();
    int tlim = qb * 64 + 64;
    for (int t = tid; t < tlim; t += 256) atomicAdd(&marg[b * 1024 + t], colbuf[t]);
}

// ---------------- entropy: marg (B,1024) -> scaled_entr (B) ----------------
__global__ __launch_bounds__(256) void entropy_kernel(const float* __restrict__ marg, float* __restrict__ out) {
    int b = blockIdx.x, tid = threadIdx.x;
    __shared__ float red[256];
    float s = 0.f;
    for (int t = tid; t < 1024; t += 256) s += marg[b * 1024 + t];
    red[tid] = s; __syncthreads();
    for (int k = 128; k > 0; k >>= 1) { if (tid < k) red[tid] += red[tid + k]; __syncthreads(); }
    float tot = red[0];
    __syncthreads();
    float e = 0.f;
    for (int t = tid; t < 1024; t += 256) {
        float p = marg[b * 1024 + t] / tot;
        if (p > 0.f) e -= p * log2f(p);
    }
    red[tid] = e; __syncthreads();
    for (int k = 128; k > 0; k >>= 1) { if (tid < k) red[tid] += red[tid + k]; __syncthreads(); }
    if (tid == 0) out[b] = red[0] * 0.1f;  // / log2(c=1024)
}

extern "C" void kernel_launch(void* const* d_in, const int* in_sizes, int n_in,
                              void* d_out, int out_size, void* d_ws, size_t ws_size,
                              hipStream_t stream) {
    const float* qinput  = (const float*)d_in[0];
    const float* kvinput = (const float*)d_in[1];
    const float* qmask   = (const float*)d_in[2];
    // d_in[3] tmask (zeros), d_in[4] qtmask (causal) — structure folded into kernels
    const float* wq = (const float*)d_in[5];
    const float* wk = (const float*)d_in[6];
    const float* wv = (const float*)d_in[7];
    const float* wo = (const float*)d_in[8];

    char* ws = (char*)d_ws;
    const size_t MB = 1024 * 1024;
    u16* Xq   = (u16*)(ws + 0);        // 8MB, reused as Pre
    u16* Xkv  = (u16*)(ws + 8 * MB);   // 8MB, reused as Vt
    u16* Wqt  = (u16*)(ws + 16 * MB);  // 2MB each
    u16* Wkt  = (u16*)(ws + 18 * MB);
    u16* Wvt  = (u16*)(ws + 20 * MB);
    u16* Wot  = (u16*)(ws + 22 * MB);
    u16* Qp   = (u16*)(ws + 24 * MB);  // 8MB each
    u16* Kp   = (u16*)(ws + 32 * MB);
    u16* Vp   = (u16*)(ws + 40 * MB);
    float* marg = (float*)(ws + 48 * MB);  // 16KB
    u16* Pre = Xq;
    u16* Vt  = Xkv;
    float* out = (float*)d_out;

    cvt_kernel<<<4096, 256, 0, stream>>>(qinput, Xq);
    cvt_kernel<<<4096, 256, 0, stream>>>(kvinput, Xkv);
    wtrans_kernel<<<dim3(16, 1, 16), 256, 0, stream>>>(wq, Wqt, 1024, 64, 64 * 1024);
    wtrans_kernel<<<dim3(16, 1, 16), 256, 0, stream>>>(wk, Wkt, 1024, 64, 64 * 1024);
    wtrans_kernel<<<dim3(16, 1, 16), 256, 0, stream>>>(wv, Wvt, 1024, 64, 64 * 1024);
    wtrans_kernel<<<dim3(1, 16, 16), 256, 0, stream>>>(wo, Wot, 64, 1024, 64);

    dim3 gg(32, 8, 1);
    gemm_kernel<<<gg, 256, 0, stream>>>(Xq,  Wqt, Qp, nullptr, nullptr);
    gemm_kernel<<<gg, 256, 0, stream>>>(Xkv, Wkt, Kp, nullptr, nullptr);
    gemm_kernel<<<gg, 256, 0, stream>>>(Xkv, Wvt, Vp, nullptr, nullptr);
    vtrans_kernel<<<dim3(16, 16, 4), 256, 0, stream>>>(Vp, Vt);   // overwrites Xkv (done with it)

    hipMemsetAsync(marg, 0, 4096 * sizeof(float), stream);
    attn_kernel<<<dim3(16, 16, 4), 256, 0, stream>>>(Qp, Kp, Vt, Pre, marg);  // Pre overwrites Xq
    entropy_kernel<<<4, 256, 0, stream>>>(marg, out + (size_t)4 * 1024 * 1024);
    gemm_kernel<<<gg, 256, 0, stream>>>(Pre, Wot, nullptr, out, qmask);
}

// Round 2
// 285.139 us; speedup vs baseline: 1.4427x; 1.4427x over previous
//
#include <hip/hip_runtime.h>
#include <hip/hip_bf16.h>

typedef unsigned short u16;
typedef __attribute__((ext_vector_type(8))) short bf16x8;
typedef __attribute__((ext_vector_type(4))) float f32x4;

#define MFMA(a, b, c) __builtin_amdgcn_mfma_f32_16x16x32_bf16(a, b, c, 0, 0, 0)

__device__ inline u16 f2bf(float f) {
    union { __hip_bfloat16 b; u16 u; } cv;
    cv.b = __float2bfloat16(f);
    return cv.u;
}

__device__ inline f32x4 zero4() {
    f32x4 v; v[0] = 0.f; v[1] = 0.f; v[2] = 0.f; v[3] = 0.f; return v;
}

// async global->LDS, 16B per lane. LDS dest = wave-uniform base + lane*16.
__device__ inline void gl_lds16(const u16* g, u16* l) {
    __builtin_amdgcn_global_load_lds(
        (const __attribute__((address_space(1))) u16*)(g),
        (__attribute__((address_space(3))) u16*)(l), 16, 0, 0);
}

// ---------------- fp32 -> bf16 elementwise (4 elems/thread) ----------------
__global__ __launch_bounds__(256) void cvt_kernel(const float* __restrict__ in, u16* __restrict__ out) {
    int i = (blockIdx.x * 256 + threadIdx.x) * 4;
    float4 v = *(const float4*)(in + i);
    u16 o[4] = { f2bf(v.x), f2bf(v.y), f2bf(v.z), f2bf(v.w) };
    *(uint2*)(out + i) = *(const uint2*)o;
}

// ---------------- per-head weight transpose fp32 -> bf16 ----------------
__global__ __launch_bounds__(256) void wtrans_kernel(const float* __restrict__ src, u16* __restrict__ dst,
                                                     int R, int C, int ho) {
    __shared__ float tile[64][65];
    int h = blockIdx.z;
    int r0 = blockIdx.x * 64, c0 = blockIdx.y * 64;
    const float* s = src + (size_t)h * R * C;
    int tid = threadIdx.x;
#pragma unroll
    for (int k = 0; k < 16; k++) {
        int idx = tid + k * 256;
        int i = idx >> 6, j = idx & 63;
        tile[i][j] = s[(size_t)(r0 + i) * C + (c0 + j)];
    }
    __syncthreads();
    u16* d = dst + (size_t)h * ho;
#pragma unroll
    for (int k = 0; k < 16; k++) {
        int idx = tid + k * 256;
        int j = idx >> 6, i = idx & 63;
        d[(size_t)(c0 + j) * 1024 + (r0 + i)] = f2bf(tile[i][j]);
    }
}

// ---------------- fused QKV projection GEMM ----------------
// grid (32, 24): ny<8 -> Q (A=Xq), 8..15 -> K (A=Xkv), 16..23 -> V (A=Xkv, transposed write).
// Weights Wqt|Wkt|Wvt contiguous, each (n=1024, k=1024) row-major bf16.
// 128x128 tile, 256 thr, global_load_lds staging.
__global__ __launch_bounds__(256) void proj_kernel(const u16* __restrict__ Xq, const u16* __restrict__ Xkv,
                                                   const u16* __restrict__ W3,
                                                   u16* __restrict__ Qp, u16* __restrict__ Kp,
                                                   u16* __restrict__ Vt) {
    __shared__ __align__(16) u16 As[128 * 32];
    __shared__ __align__(16) u16 Bs[128 * 32];
    int tid = threadIdx.x;
    int ny = blockIdx.y;
    int sel = ny >> 3;
    const u16* A  = (sel == 0) ? Xq : Xkv;
    const u16* Bt = W3 + (size_t)sel * 1024 * 1024;
    int m0 = blockIdx.x * 128, n0 = (ny & 7) * 128;
    int w = tid >> 6, lane = tid & 63, quad = lane >> 4, c = lane & 15;
    int mw = (w & 1) * 64, nw = (w >> 1) * 64;
    f32x4 acc[4][4];
#pragma unroll
    for (int i = 0; i < 4; i++)
#pragma unroll
        for (int j = 0; j < 4; j++) acc[i][j] = zero4();

    for (int k0 = 0; k0 < 1024; k0 += 32) {
        __syncthreads();
#pragma unroll
        for (int s = 0; s < 2; s++) {
            int ch = s * 256 + w * 64 + lane;
            int r = ch >> 2, cc = (ch & 3) * 8;
            gl_lds16(&A[(size_t)(m0 + r) * 1024 + k0 + cc],  &As[(s * 256 + w * 64) * 8]);
            gl_lds16(&Bt[(size_t)(n0 + r) * 1024 + k0 + cc], &Bs[(s * 256 + w * 64) * 8]);
        }
        __syncthreads();
        bf16x8 af[4], bfr[4];
#pragma unroll
        for (int i = 0; i < 4; i++) af[i] = *(const bf16x8*)&As[(mw + i * 16 + c) * 32 + quad * 8];
#pragma unroll
        for (int j = 0; j < 4; j++) bfr[j] = *(const bf16x8*)&Bs[(nw + j * 16 + c) * 32 + quad * 8];
#pragma unroll
        for (int i = 0; i < 4; i++)
#pragma unroll
            for (int j = 0; j < 4; j++) acc[i][j] = MFMA(af[i], bfr[j], acc[i][j]);
    }
#pragma unroll
    for (int i = 0; i < 4; i++) {
#pragma unroll
        for (int r = 0; r < 4; r++) {
            int row = m0 + mw + i * 16 + quad * 4 + r;
#pragma unroll
            for (int j = 0; j < 4; j++) {
                int col = n0 + nw + j * 16 + c;
                u16 v = f2bf(acc[i][j][r]);
                if (sel == 0)      Qp[(size_t)row * 1024 + col] = v;
                else if (sel == 1) Kp[(size_t)row * 1024 + col] = v;
                else {
                    int b = row >> 10, t = row & 1023;
                    Vt[((size_t)(b * 16 + (col >> 6)) * 64 + (col & 63)) * 1024 + t] = v;
                }
            }
        }
    }
}

// ---------------- output projection GEMM: out = (Pre @ Wot^T) * (1-qmask) ----------------
__global__ __launch_bounds__(256) void gemmo_kernel(const u16* __restrict__ A, const u16* __restrict__ Bt,
                                                    float* __restrict__ Cf, const float* __restrict__ qmask) {
    __shared__ __align__(16) u16 As[128 * 32];
    __shared__ __align__(16) u16 Bs[128 * 32];
    int tid = threadIdx.x;
    int m0 = blockIdx.x * 128, n0 = blockIdx.y * 128;
    int w = tid >> 6, lane = tid & 63, quad = lane >> 4, c = lane & 15;
    int mw = (w & 1) * 64, nw = (w >> 1) * 64;
    f32x4 acc[4][4];
#pragma unroll
    for (int i = 0; i < 4; i++)
#pragma unroll
        for (int j = 0; j < 4; j++) acc[i][j] = zero4();

    for (int k0 = 0; k0 < 1024; k0 += 32) {
        __syncthreads();
#pragma unroll
        for (int s = 0; s < 2; s++) {
            int ch = s * 256 + w * 64 + lane;
            int r = ch >> 2, cc = (ch & 3) * 8;
            gl_lds16(&A[(size_t)(m0 + r) * 1024 + k0 + cc],  &As[(s * 256 + w * 64) * 8]);
            gl_lds16(&Bt[(size_t)(n0 + r) * 1024 + k0 + cc], &Bs[(s * 256 + w * 64) * 8]);
        }
        __syncthreads();
        bf16x8 af[4], bfr[4];
#pragma unroll
        for (int i = 0; i < 4; i++) af[i] = *(const bf16x8*)&As[(mw + i * 16 + c) * 32 + quad * 8];
#pragma unroll
        for (int j = 0; j < 4; j++) bfr[j] = *(const bf16x8*)&Bs[(nw + j * 16 + c) * 32 + quad * 8];
#pragma unroll
        for (int i = 0; i < 4; i++)
#pragma unroll
            for (int j = 0; j < 4; j++) acc[i][j] = MFMA(af[i], bfr[j], acc[i][j]);
    }
#pragma unroll
    for (int i = 0; i < 4; i++) {
#pragma unroll
        for (int r = 0; r < 4; r++) {
            int row = m0 + mw + i * 16 + quad * 4 + r;
            float scale = 1.0f - qmask[row];
#pragma unroll
            for (int j = 0; j < 4; j++) {
                int col = n0 + nw + j * 16 + c;
                Cf[(size_t)row * 1024 + col] = acc[i][j][r] * scale;
            }
        }
    }
}

// ---------------- flash attention, fixed m=0, paired causal balancing ----------------
// grid (8, 16, 4). wave w handles q-tile pair {p, 63-p}, p = bx*4+w. 64-wide t-chunks.
__global__ __launch_bounds__(256) void attn_kernel(const u16* __restrict__ Qp, const u16* __restrict__ Kp,
                                                   const u16* __restrict__ Vt, u16* __restrict__ Pre,
                                                   float* __restrict__ marg) {
    __shared__ float colbuf[1024];
    __shared__ __align__(16) u16 plds[4][16 * 72];
    int tid = threadIdx.x;
    int h = blockIdx.y, b = blockIdx.z;
    for (int i = tid; i < 1024; i += 256) colbuf[i] = 0.f;
    __syncthreads();

    int w = tid >> 6, lane = tid & 63, quad = lane >> 4, c = lane & 15;
    int p = blockIdx.x * 4 + w;
    u16* pl = plds[w];
    const u16* kbase = Kp + (size_t)b * 1024 * 1024 + h * 64;
    const u16* vbase = Vt + (size_t)(b * 16 + h) * 64 * 1024;
    const float sc = 0.125f * 1.4426950408889634f;  // kscale * log2(e)

    auto process_tile = [&](int q0) {
        const u16* qrow = Qp + (size_t)(b * 1024 + q0 + c) * 1024 + h * 64;
        bf16x8 aq0 = *(const bf16x8*)(qrow + quad * 8);
        bf16x8 aq1 = *(const bf16x8*)(qrow + 32 + quad * 8);
        f32x4 o[4];
#pragma unroll
        for (int i = 0; i < 4; i++) o[i] = zero4();
        float l[4] = {0.f, 0.f, 0.f, 0.f};
        int nt = q0 + 16;
        int qg[4];
#pragma unroll
        for (int r = 0; r < 4; r++) qg[r] = q0 + quad * 4 + r;

        for (int t0 = 0; t0 < nt; t0 += 64) {
            f32x4 s[4];
#pragma unroll
            for (int j = 0; j < 4; j++) {
                const u16* kp = kbase + (size_t)(t0 + j * 16 + c) * 1024 + quad * 8;
                bf16x8 b0 = *(const bf16x8*)kp;
                bf16x8 b1 = *(const bf16x8*)(kp + 32);
                s[j] = MFMA(aq0, b0, zero4());
                s[j] = MFMA(aq1, b1, s[j]);
            }
#pragma unroll
            for (int j = 0; j < 4; j++) {
                int t = t0 + j * 16 + c;
#pragma unroll
                for (int r = 0; r < 4; r++) {
                    float e = (t <= qg[r]) ? exp2f(s[j][r] * sc) : 0.f;
                    l[r] += e;
                    pl[(quad * 4 + r) * 72 + j * 16 + c] = f2bf(e);
                }
            }
            asm volatile("s_waitcnt lgkmcnt(0)" ::: "memory");
            bf16x8 ap0 = *(const bf16x8*)&pl[c * 72 + quad * 8];
            bf16x8 ap1 = *(const bf16x8*)&pl[c * 72 + 32 + quad * 8];
#pragma unroll
            for (int vt = 0; vt < 4; vt++) {
                const u16* vp = vbase + (size_t)(vt * 16 + c) * 1024 + t0 + quad * 8;
                bf16x8 bv0 = *(const bf16x8*)vp;
                bf16x8 bv1 = *(const bf16x8*)(vp + 32);
                o[vt] = MFMA(ap0, bv0, o[vt]);
                o[vt] = MFMA(ap1, bv1, o[vt]);
            }
        }
        float invl[4];
#pragma unroll
        for (int r = 0; r < 4; r++) {
            float lr = l[r];
#pragma unroll
            for (int d = 1; d < 16; d <<= 1) lr += __shfl_xor(lr, d);
            invl[r] = 1.0f / lr;
        }
#pragma unroll
        for (int vt = 0; vt < 4; vt++)
#pragma unroll
            for (int r = 0; r < 4; r++) {
                size_t row = (size_t)(b * 1024 + q0 + quad * 4 + r);
                Pre[row * 1024 + h * 64 + vt * 16 + c] = f2bf(o[vt][r] * invl[r]);
            }

        // phase 2: column marginals sum_q att[q,t]*(q+1), att = e*invl
        float wr[4];
#pragma unroll
        for (int r = 0; r < 4; r++) wr[r] = (float)(qg[r] + 1) * invl[r];
        for (int t0 = 0; t0 < nt; t0 += 64) {
            f32x4 s[4];
#pragma unroll
            for (int j = 0; j < 4; j++) {
                const u16* kp = kbase + (size_t)(t0 + j * 16 + c) * 1024 + quad * 8;
                bf16x8 b0 = *(const bf16x8*)kp;
                bf16x8 b1 = *(const bf16x8*)(kp + 32);
                s[j] = MFMA(aq0, b0, zero4());
                s[j] = MFMA(aq1, b1, s[j]);
            }
            float cs[4];
#pragma unroll
            for (int j = 0; j < 4; j++) {
                int t = t0 + j * 16 + c;
                float a = 0.f;
#pragma unroll
                for (int r = 0; r < 4; r++)
                    a += (t <= qg[r]) ? exp2f(s[j][r] * sc) * wr[r] : 0.f;
                a += __shfl_xor(a, 16);
                a += __shfl_xor(a, 32);
                cs[j] = a;
            }
            float v = (quad == 0) ? cs[0] : (quad == 1) ? cs[1] : (quad == 2) ? cs[2] : cs[3];
            atomicAdd(&colbuf[t0 + lane], v);
        }
    };

    process_tile(16 * p);
    process_tile(16 * (63 - p));

    __syncthreads();
    for (int t = tid; t < 1024; t += 256) {
        float v = colbuf[t];
        if (v != 0.f) atomicAdd(&marg[b * 1024 + t], v);
    }
}

// ---------------- entropy: marg (B,1024) -> scaled_entr (B) ----------------
__global__ __launch_bounds__(256) void entropy_kernel(const float* __restrict__ marg, float* __restrict__ out) {
    int b = blockIdx.x, tid = threadIdx.x;
    __shared__ float red[256];
    float s = 0.f;
    for (int t = tid; t < 1024; t += 256) s += marg[b * 1024 + t];
    red[tid] = s; __syncthreads();
    for (int k = 128; k > 0; k >>= 1) { if (tid < k) red[tid] += red[tid + k]; __syncthreads(); }
    float tot = red[0];
    __syncthreads();
    float e = 0.f;
    for (int t = tid; t < 1024; t += 256) {
        float p = marg[b * 1024 + t] / tot;
        if (p > 0.f) e -= p * log2f(p);
    }
    red[tid] = e; __syncthreads();
    for (int k = 128; k > 0; k >>= 1) { if (tid < k) red[tid] += red[tid + k]; __syncthreads(); }
    if (tid == 0) out[b] = red[0] * 0.1f;  // / log2(c=1024)
}

extern "C" void kernel_launch(void* const* d_in, const int* in_sizes, int n_in,
                              void* d_out, int out_size, void* d_ws, size_t ws_size,
                              hipStream_t stream) {
    const float* qinput  = (const float*)d_in[0];
    const float* kvinput = (const float*)d_in[1];
    const float* qmask   = (const float*)d_in[2];
    const float* wq = (const float*)d_in[5];
    const float* wk = (const float*)d_in[6];
    const float* wv = (const float*)d_in[7];
    const float* wo = (const float*)d_in[8];

    char* ws = (char*)d_ws;
    const size_t MB = 1024 * 1024;
    u16* Xq   = (u16*)(ws + 0);        // 8MB, reused as Pre after Q-proj consumed
    u16* Xkv  = (u16*)(ws + 8 * MB);   // 8MB
    u16* W3   = (u16*)(ws + 16 * MB);  // Wqt|Wkt|Wvt contiguous, 2MB each
    u16* Wot  = (u16*)(ws + 22 * MB);
    u16* Qp   = (u16*)(ws + 24 * MB);  // 8MB
    u16* Kp   = (u16*)(ws + 32 * MB);  // 8MB
    u16* Vt   = (u16*)(ws + 40 * MB);  // 8MB (B,H,V,T)
    float* marg = (float*)(ws + 48 * MB);  // 16KB
    u16* Pre = Xq;
    float* out = (float*)d_out;

    cvt_kernel<<<4096, 256, 0, stream>>>(qinput, Xq);
    cvt_kernel<<<4096, 256, 0, stream>>>(kvinput, Xkv);
    wtrans_kernel<<<dim3(16, 1, 16), 256, 0, stream>>>(wq, W3,                  1024, 64, 64 * 1024);
    wtrans_kernel<<<dim3(16, 1, 16), 256, 0, stream>>>(wk, W3 + 1024 * 1024,    1024, 64, 64 * 1024);
    wtrans_kernel<<<dim3(16, 1, 16), 256, 0, stream>>>(wv, W3 + 2 * 1024 * 1024, 1024, 64, 64 * 1024);
    wtrans_kernel<<<dim3(1, 16, 16), 256, 0, stream>>>(wo, Wot, 64, 1024, 64);

    proj_kernel<<<dim3(32, 24), 256, 0, stream>>>(Xq, Xkv, W3, Qp, Kp, Vt);

    hipMemsetAsync(marg, 0, 4096 * sizeof(float), stream);
    attn_kernel<<<dim3(8, 16, 4), 256, 0, stream>>>(Qp, Kp, Vt, Pre, marg);  // Pre overwrites Xq
    entropy_kernel<<<4, 256, 0, stream>>>(marg, out + (size_t)4 * 1024 * 1024);
    gemmo_kernel<<<dim3(32, 8), 256, 0, stream>>>(Pre, Wot, out, qmask);
}

// Round 3
// 261.911 us; speedup vs baseline: 1.5706x; 1.0887x over previous
//
#include <hip/hip_runtime.h>
#include <hip/hip_bf16.h>

typedef unsigned short u16;
typedef __attribute__((ext_vector_type(8))) short bf16x8;
typedef __attribute__((ext_vector_type(4))) float f32x4;

#define MFMA(a, b, c) __builtin_amdgcn_mfma_f32_16x16x32_bf16(a, b, c, 0, 0, 0)

__device__ inline u16 f2bf(float f) {
    union { __hip_bfloat16 b; u16 u; } cv;
    cv.b = __float2bfloat16(f);
    return cv.u;
}

__device__ inline f32x4 zero4() {
    f32x4 v; v[0] = 0.f; v[1] = 0.f; v[2] = 0.f; v[3] = 0.f; return v;
}

// async global->LDS, 16B per lane. LDS dest must be wave-uniform base (+lane*16 implicit).
__device__ inline void gl_lds16(const u16* g, u16* l) {
    __builtin_amdgcn_global_load_lds(
        (const __attribute__((address_space(1))) u16*)(g),
        (__attribute__((address_space(3))) u16*)(l), 16, 0, 0);
}

// ---------------- fp32 -> bf16, both inputs in one dispatch ----------------
__global__ __launch_bounds__(256) void cvt2_kernel(const float* __restrict__ qa, const float* __restrict__ kva,
                                                   u16* __restrict__ oq, u16* __restrict__ okv) {
    int bid = blockIdx.x;
    const float* in = (bid < 4096) ? qa : kva;
    u16* out = (bid < 4096) ? oq : okv;
    int i = (((bid & 4095) * 256) + threadIdx.x) * 4;
    float4 v = *(const float4*)(in + i);
    u16 o[4] = { f2bf(v.x), f2bf(v.y), f2bf(v.z), f2bf(v.w) };
    *(uint2*)(out + i) = *(const uint2*)o;
}

// ---------------- all 4 weight transposes fp32 -> bf16, one dispatch ----------------
// by<3: wq/wk/wv (R=1024,C=64): Wt[(h*64+d)*1024+m]. by=3: wo (R=64,C=1024): Wot[m*1024+h*64+v].
__global__ __launch_bounds__(256) void wtrans4_kernel(const float* __restrict__ wq, const float* __restrict__ wk,
                                                      const float* __restrict__ wv, const float* __restrict__ wo,
                                                      u16* __restrict__ W3, u16* __restrict__ Wot) {
    __shared__ float tile[64][65];
    int by = blockIdx.y, h = blockIdx.z, tid = threadIdx.x;
    const float* src; u16* dst; int R, C, ho, r0, c0;
    if (by == 3) { src = wo; dst = Wot; R = 64; C = 1024; ho = 64; r0 = 0; c0 = blockIdx.x * 64; }
    else {
        src = (by == 0) ? wq : (by == 1) ? wk : wv;
        dst = W3 + (size_t)by * 1024 * 1024;
        R = 1024; C = 64; ho = 64 * 1024; r0 = blockIdx.x * 64; c0 = 0;
    }
    const float* s = src + (size_t)h * R * C;
#pragma unroll
    for (int k = 0; k < 16; k++) {
        int idx = tid + k * 256;
        int i = idx >> 6, j = idx & 63;
        tile[i][j] = s[(size_t)(r0 + i) * C + (c0 + j)];
    }
    __syncthreads();
    u16* d = dst + (size_t)h * ho;
#pragma unroll
    for (int k = 0; k < 16; k++) {
        int idx = tid + k * 256;
        int j = idx >> 6, i = idx & 63;
        d[(size_t)(c0 + j) * 1024 + (r0 + i)] = f2bf(tile[i][j]);
    }
}

// ---------------- fused QKV projection GEMM (unchanged from R2) ----------------
__global__ __launch_bounds__(256) void proj_kernel(const u16* __restrict__ Xq, const u16* __restrict__ Xkv,
                                                   const u16* __restrict__ W3,
                                                   u16* __restrict__ Qp, u16* __restrict__ Kp,
                                                   u16* __restrict__ Vt) {
    __shared__ __align__(16) u16 As[128 * 32];
    __shared__ __align__(16) u16 Bs[128 * 32];
    int tid = threadIdx.x;
    int ny = blockIdx.y;
    int sel = ny >> 3;
    const u16* A  = (sel == 0) ? Xq : Xkv;
    const u16* Bt = W3 + (size_t)sel * 1024 * 1024;
    int m0 = blockIdx.x * 128, n0 = (ny & 7) * 128;
    int w = tid >> 6, lane = tid & 63, quad = lane >> 4, c = lane & 15;
    int mw = (w & 1) * 64, nw = (w >> 1) * 64;
    f32x4 acc[4][4];
#pragma unroll
    for (int i = 0; i < 4; i++)
#pragma unroll
        for (int j = 0; j < 4; j++) acc[i][j] = zero4();

    for (int k0 = 0; k0 < 1024; k0 += 32) {
        __syncthreads();
#pragma unroll
        for (int s = 0; s < 2; s++) {
            int ch = s * 256 + w * 64 + lane;
            int r = ch >> 2, cc = (ch & 3) * 8;
            gl_lds16(&A[(size_t)(m0 + r) * 1024 + k0 + cc],  &As[(s * 256 + w * 64) * 8]);
            gl_lds16(&Bt[(size_t)(n0 + r) * 1024 + k0 + cc], &Bs[(s * 256 + w * 64) * 8]);
        }
        asm volatile("s_waitcnt vmcnt(0)" ::: "memory");
        __syncthreads();
        bf16x8 af[4], bfr[4];
#pragma unroll
        for (int i = 0; i < 4; i++) af[i] = *(const bf16x8*)&As[(mw + i * 16 + c) * 32 + quad * 8];
#pragma unroll
        for (int j = 0; j < 4; j++) bfr[j] = *(const bf16x8*)&Bs[(nw + j * 16 + c) * 32 + quad * 8];
#pragma unroll
        for (int i = 0; i < 4; i++)
#pragma unroll
            for (int j = 0; j < 4; j++) acc[i][j] = MFMA(af[i], bfr[j], acc[i][j]);
    }
#pragma unroll
    for (int i = 0; i < 4; i++) {
#pragma unroll
        for (int r = 0; r < 4; r++) {
            int row = m0 + mw + i * 16 + quad * 4 + r;
#pragma unroll
            for (int j = 0; j < 4; j++) {
                int col = n0 + nw + j * 16 + c;
                u16 v = f2bf(acc[i][j][r]);
                if (sel == 0)      Qp[(size_t)row * 1024 + col] = v;
                else if (sel == 1) Kp[(size_t)row * 1024 + col] = v;
                else {
                    int b = row >> 10, t = row & 1023;
                    Vt[((size_t)(b * 16 + (col >> 6)) * 64 + (col & 63)) * 1024 + t] = v;
                }
            }
        }
    }
}

// ---------------- output projection GEMM (unchanged from R2) ----------------
__global__ __launch_bounds__(256) void gemmo_kernel(const u16* __restrict__ A, const u16* __restrict__ Bt,
                                                    float* __restrict__ Cf, const float* __restrict__ qmask) {
    __shared__ __align__(16) u16 As[128 * 32];
    __shared__ __align__(16) u16 Bs[128 * 32];
    int tid = threadIdx.x;
    int m0 = blockIdx.x * 128, n0 = blockIdx.y * 128;
    int w = tid >> 6, lane = tid & 63, quad = lane >> 4, c = lane & 15;
    int mw = (w & 1) * 64, nw = (w >> 1) * 64;
    f32x4 acc[4][4];
#pragma unroll
    for (int i = 0; i < 4; i++)
#pragma unroll
        for (int j = 0; j < 4; j++) acc[i][j] = zero4();

    for (int k0 = 0; k0 < 1024; k0 += 32) {
        __syncthreads();
#pragma unroll
        for (int s = 0; s < 2; s++) {
            int ch = s * 256 + w * 64 + lane;
            int r = ch >> 2, cc = (ch & 3) * 8;
            gl_lds16(&A[(size_t)(m0 + r) * 1024 + k0 + cc],  &As[(s * 256 + w * 64) * 8]);
            gl_lds16(&Bt[(size_t)(n0 + r) * 1024 + k0 + cc], &Bs[(s * 256 + w * 64) * 8]);
        }
        asm volatile("s_waitcnt vmcnt(0)" ::: "memory");
        __syncthreads();
        bf16x8 af[4], bfr[4];
#pragma unroll
        for (int i = 0; i < 4; i++) af[i] = *(const bf16x8*)&As[(mw + i * 16 + c) * 32 + quad * 8];
#pragma unroll
        for (int j = 0; j < 4; j++) bfr[j] = *(const bf16x8*)&Bs[(nw + j * 16 + c) * 32 + quad * 8];
#pragma unroll
        for (int i = 0; i < 4; i++)
#pragma unroll
            for (int j = 0; j < 4; j++) acc[i][j] = MFMA(af[i], bfr[j], acc[i][j]);
    }
#pragma unroll
    for (int i = 0; i < 4; i++) {
#pragma unroll
        for (int r = 0; r < 4; r++) {
            int row = m0 + mw + i * 16 + quad * 4 + r;
            float scale = 1.0f - qmask[row];
#pragma unroll
            for (int j = 0; j < 4; j++) {
                int col = n0 + nw + j * 16 + c;
                Cf[(size_t)row * 1024 + col] = acc[i][j][r] * scale;
            }
        }
    }
}

// ---------------- flash attention, cooperative LDS staging, fixed m=0 ----------------
// grid (16,16,4). Block bx covers q-tiles 4bx..4bx+3 (wave w -> tile 4bx+w).
// All 4 tiles need exactly bx+1 chunks of 64 t -> uniform barriers, shared K/V staging.
// K/V staged via global_load_lds with XOR swizzle (unit' = unit ^ (row&7)) applied on
// the GLOBAL address so the DMA lane layout stays contiguous; frag ds_read_b128s are
// then 2-way-conflict-free (free per m136).
__global__ __launch_bounds__(256) void attn_kernel(const u16* __restrict__ Qp, const u16* __restrict__ Kp,
                                                   const u16* __restrict__ Vt, u16* __restrict__ Pre,
                                                   float* __restrict__ marg) {
    __shared__ __align__(16) u16 Ks[64 * 64];
    __shared__ __align__(16) u16 Vs[64 * 64];
    __shared__ __align__(16) u16 plds[4][16 * 72];
    __shared__ float colbuf[1024];
    int tid = threadIdx.x;
    int bx = blockIdx.x, h = blockIdx.y, b = blockIdx.z;
    int w = tid >> 6, lane = tid & 63, quad = lane >> 4, c = lane & 15;
    int tmax = 64 * (bx + 1);
    for (int i = tid; i < tmax; i += 256) colbuf[i] = 0.f;

    int q0 = bx * 64 + w * 16;
    const u16* qrow = Qp + (size_t)(b * 1024 + q0 + c) * 1024 + h * 64;
    bf16x8 aq0 = *(const bf16x8*)(qrow + quad * 8);
    bf16x8 aq1 = *(const bf16x8*)(qrow + 32 + quad * 8);

    const u16* kb = Kp + (size_t)b * 1024 * 1024 + h * 64;
    const u16* vb = Vt + (size_t)(b * 16 + h) * 64 * 1024;
    u16* pl = plds[w];
    const float sc = 0.125f * 1.4426950408889634f;  // kscale * log2(e)

    // staging geometry: idx = s*256 + w*64 + lane; row = idx>>3 (s=1 -> +32), unit = idx&7
    int idx0 = w * 64 + lane;
    int row0 = idx0 >> 3;
    int lu = (idx0 & 7) ^ (row0 & 7);  // logical unit to fetch (row0+32 has same row&7)
    int sw = c & 7;                    // read-side swizzle key (R&7 == c&7 for R = j*16+c)
    int su0 = (quad ^ sw) * 8;         // storage offset (u16) of logical unit 'quad'
    int su1 = ((quad ^ 4) ^ sw) * 8;   // storage offset of logical unit 'quad+4'

    f32x4 o[4];
#pragma unroll
    for (int i = 0; i < 4; i++) o[i] = zero4();
    float l[4] = {0.f, 0.f, 0.f, 0.f};
    int qg[4];
#pragma unroll
    for (int r = 0; r < 4; r++) qg[r] = q0 + quad * 4 + r;
    int tlast = 64 * bx;

    // ---------------- phase 1: PV + row sums ----------------
    for (int t0 = 0; t0 <= tlast; t0 += 64) {
        __syncthreads();
        gl_lds16(kb + (size_t)(t0 + row0) * 1024 + lu * 8,      Ks + w * 64 * 8);
        gl_lds16(kb + (size_t)(t0 + row0 + 32) * 1024 + lu * 8, Ks + (256 + w * 64) * 8);
        gl_lds16(vb + (size_t)row0 * 1024 + t0 + lu * 8,        Vs + w * 64 * 8);
        gl_lds16(vb + (size_t)(row0 + 32) * 1024 + t0 + lu * 8, Vs + (256 + w * 64) * 8);
        asm volatile("s_waitcnt vmcnt(0)" ::: "memory");
        __syncthreads();
        f32x4 s[4];
#pragma unroll
        for (int j = 0; j < 4; j++) {
            const u16* kr = Ks + (j * 16 + c) * 64;
            bf16x8 b0 = *(const bf16x8*)(kr + su0);
            bf16x8 b1 = *(const bf16x8*)(kr + su1);
            s[j] = MFMA(aq0, b0, zero4());
            s[j] = MFMA(aq1, b1, s[j]);
        }
        if (t0 < tlast) {  // full chunk, no mask
#pragma unroll
            for (int j = 0; j < 4; j++)
#pragma unroll
                for (int r = 0; r < 4; r++) {
                    float e = exp2f(s[j][r] * sc);
                    l[r] += e;
                    pl[(quad * 4 + r) * 72 + j * 16 + c] = f2bf(e);
                }
        } else {  // diagonal chunk
#pragma unroll
            for (int j = 0; j < 4; j++) {
                int t = t0 + j * 16 + c;
#pragma unroll
                for (int r = 0; r < 4; r++) {
                    float e = (t <= qg[r]) ? exp2f(s[j][r] * sc) : 0.f;
                    l[r] += e;
                    pl[(quad * 4 + r) * 72 + j * 16 + c] = f2bf(e);
                }
            }
        }
        asm volatile("s_waitcnt lgkmcnt(0)" ::: "memory");
        bf16x8 ap0 = *(const bf16x8*)&pl[c * 72 + quad * 8];
        bf16x8 ap1 = *(const bf16x8*)&pl[c * 72 + 32 + quad * 8];
#pragma unroll
        for (int vt = 0; vt < 4; vt++) {
            const u16* vr = Vs + (vt * 16 + c) * 64;
            bf16x8 bv0 = *(const bf16x8*)(vr + su0);
            bf16x8 bv1 = *(const bf16x8*)(vr + su1);
            o[vt] = MFMA(ap0, bv0, o[vt]);
            o[vt] = MFMA(ap1, bv1, o[vt]);
        }
    }

    float invl[4];
#pragma unroll
    for (int r = 0; r < 4; r++) {
        float lr = l[r];
#pragma unroll
        for (int d = 1; d < 16; d <<= 1) lr += __shfl_xor(lr, d);
        invl[r] = 1.0f / lr;
    }
#pragma unroll
    for (int vt = 0; vt < 4; vt++)
#pragma unroll
        for (int r = 0; r < 4; r++) {
            size_t row = (size_t)(b * 1024 + q0 + quad * 4 + r);
            Pre[row * 1024 + h * 64 + vt * 16 + c] = f2bf(o[vt][r] * invl[r]);
        }

    // ---------------- phase 2: column marginals sum_q att[q,t]*(q+1) ----------------
    float wr[4];
#pragma unroll
    for (int r = 0; r < 4; r++) wr[r] = (float)(qg[r] + 1) * invl[r];
    for (int t0 = 0; t0 <= tlast; t0 += 64) {
        __syncthreads();
        gl_lds16(kb + (size_t)(t0 + row0) * 1024 + lu * 8,      Ks + w * 64 * 8);
        gl_lds16(kb + (size_t)(t0 + row0 + 32) * 1024 + lu * 8, Ks + (256 + w * 64) * 8);
        asm volatile("s_waitcnt vmcnt(0)" ::: "memory");
        __syncthreads();
        f32x4 s[4];
#pragma unroll
        for (int j = 0; j < 4; j++) {
            const u16* kr = Ks + (j * 16 + c) * 64;
            bf16x8 b0 = *(const bf16x8*)(kr + su0);
            bf16x8 b1 = *(const bf16x8*)(kr + su1);
            s[j] = MFMA(aq0, b0, zero4());
            s[j] = MFMA(aq1, b1, s[j]);
        }
        float a[4];
        if (t0 < tlast) {
#pragma unroll
            for (int j = 0; j < 4; j++) {
                float aj = 0.f;
#pragma unroll
                for (int r = 0; r < 4; r++) aj += exp2f(s[j][r] * sc) * wr[r];
                aj += __shfl_xor(aj, 16);
                aj += __shfl_xor(aj, 32);
                a[j] = aj;
            }
        } else {
#pragma unroll
            for (int j = 0; j < 4; j++) {
                int t = t0 + j * 16 + c;
                float aj = 0.f;
#pragma unroll
                for (int r = 0; r < 4; r++) aj += (t <= qg[r]) ? exp2f(s[j][r] * sc) * wr[r] : 0.f;
                aj += __shfl_xor(aj, 16);
                aj += __shfl_xor(aj, 32);
                a[j] = aj;
            }
        }
        float v = (quad == 0) ? a[0] : (quad == 1) ? a[1] : (quad == 2) ? a[2] : a[3];
        atomicAdd(&colbuf[t0 + lane], v);
    }
    __syncthreads();
    for (int t = tid; t < tmax; t += 256) atomicAdd(&marg[b * 1024 + t], colbuf[t]);
}

// ---------------- entropy: marg (B,1024) -> scaled_entr (B) ----------------
__global__ __launch_bounds__(256) void entropy_kernel(const float* __restrict__ marg, float* __restrict__ out) {
    int b = blockIdx.x, tid = threadIdx.x;
    __shared__ float red[256];
    float s = 0.f;
    for (int t = tid; t < 1024; t += 256) s += marg[b * 1024 + t];
    red[tid] = s; __syncthreads();
    for (int k = 128; k > 0; k >>= 1) { if (tid < k) red[tid] += red[tid + k]; __syncthreads(); }
    float tot = red[0];
    __syncthreads();
    float e = 0.f;
    for (int t = tid; t < 1024; t += 256) {
        float p = marg[b * 1024 + t] / tot;
        if (p > 0.f) e -= p * log2f(p);
    }
    red[tid] = e; __syncthreads();
    for (int k = 128; k > 0; k >>= 1) { if (tid < k) red[tid] += red[tid + k]; __syncthreads(); }
    if (tid == 0) out[b] = red[0] * 0.1f;  // / log2(c=1024)
}

extern "C" void kernel_launch(void* const* d_in, const int* in_sizes, int n_in,
                              void* d_out, int out_size, void* d_ws, size_t ws_size,
                              hipStream_t stream) {
    const float* qinput  = (const float*)d_in[0];
    const float* kvinput = (const float*)d_in[1];
    const float* qmask   = (const float*)d_in[2];
    const float* wq = (const float*)d_in[5];
    const float* wk = (const float*)d_in[6];
    const float* wv = (const float*)d_in[7];
    const float* wo = (const float*)d_in[8];

    char* ws = (char*)d_ws;
    const size_t MB = 1024 * 1024;
    u16* Xq   = (u16*)(ws + 0);        // 8MB, reused as Pre after Q-proj consumed
    u16* Xkv  = (u16*)(ws + 8 * MB);   // 8MB
    u16* W3   = (u16*)(ws + 16 * MB);  // Wqt|Wkt|Wvt contiguous, 2MB each
    u16* Wot  = (u16*)(ws + 22 * MB);
    u16* Qp   = (u16*)(ws + 24 * MB);  // 8MB
    u16* Kp   = (u16*)(ws + 32 * MB);  // 8MB
    u16* Vt   = (u16*)(ws + 40 * MB);  // 8MB (B,H,V,T)
    float* marg = (float*)(ws + 48 * MB);  // 16KB
    u16* Pre = Xq;
    float* out = (float*)d_out;

    cvt2_kernel<<<8192, 256, 0, stream>>>(qinput, kvinput, Xq, Xkv);
    wtrans4_kernel<<<dim3(16, 4, 16), 256, 0, stream>>>(wq, wk, wv, wo, W3, Wot);
    proj_kernel<<<dim3(32, 24), 256, 0, stream>>>(Xq, Xkv, W3, Qp, Kp, Vt);

    hipMemsetAsync(marg, 0, 4096 * sizeof(float), stream);
    attn_kernel<<<dim3(16, 16, 4), 256, 0, stream>>>(Qp, Kp, Vt, Pre, marg);  // Pre overwrites Xq
    entropy_kernel<<<4, 256, 0, stream>>>(marg, out + (size_t)4 * 1024 * 1024);
    gemmo_kernel<<<dim3(32, 8), 256, 0, stream>>>(Pre, Wot, out, qmask);
}

// Round 4
// 225.229 us; speedup vs baseline: 1.8264x; 1.1629x over previous
//
#include <hip/hip_runtime.h>
#include <hip/hip_bf16.h>

typedef unsigned short u16;
typedef __attribute__((ext_vector_type(8))) short bf16x8;
typedef __attribute__((ext_vector_type(4))) float f32x4;

#define MFMA(a, b, c) __builtin_amdgcn_mfma_f32_16x16x32_bf16(a, b, c, 0, 0, 0)

__device__ inline u16 f2bf(float f) {
    union { __hip_bfloat16 b; u16 u; } cv;
    cv.b = __float2bfloat16(f);
    return cv.u;
}

__device__ inline f32x4 zero4() {
    f32x4 v; v[0] = 0.f; v[1] = 0.f; v[2] = 0.f; v[3] = 0.f; return v;
}

// async global->LDS, 16B per lane. LDS dest must be wave-uniform base (+lane*16 implicit).
__device__ inline void gl_lds16(const u16* g, u16* l) {
    __builtin_amdgcn_global_load_lds(
        (const __attribute__((address_space(1))) u16*)(g),
        (__attribute__((address_space(3))) u16*)(l), 16, 0, 0);
}

// raw barrier: drains LDS ops only, leaves global_load_lds (vmcnt) in flight
__device__ inline void barrier_nodrain() {
    asm volatile("s_waitcnt lgkmcnt(0)\ns_barrier" ::: "memory");
}

// ---------------- fp32 -> bf16, both inputs in one dispatch ----------------
__global__ __launch_bounds__(256) void cvt2_kernel(const float* __restrict__ qa, const float* __restrict__ kva,
                                                   u16* __restrict__ oq, u16* __restrict__ okv) {
    int bid = blockIdx.x;
    const float* in = (bid < 4096) ? qa : kva;
    u16* out = (bid < 4096) ? oq : okv;
    int i = (((bid & 4095) * 256) + threadIdx.x) * 4;
    float4 v = *(const float4*)(in + i);
    u16 o[4] = { f2bf(v.x), f2bf(v.y), f2bf(v.z), f2bf(v.w) };
    *(uint2*)(out + i) = *(const uint2*)o;
}

// ---------------- all 4 weight transposes fp32 -> bf16, one dispatch ----------------
__global__ __launch_bounds__(256) void wtrans4_kernel(const float* __restrict__ wq, const float* __restrict__ wk,
                                                      const float* __restrict__ wv, const float* __restrict__ wo,
                                                      u16* __restrict__ W3, u16* __restrict__ Wot) {
    __shared__ float tile[64][65];
    int by = blockIdx.y, h = blockIdx.z, tid = threadIdx.x;
    const float* src; u16* dst; int R, C, ho, r0, c0;
    if (by == 3) { src = wo; dst = Wot; R = 64; C = 1024; ho = 64; r0 = 0; c0 = blockIdx.x * 64; }
    else {
        src = (by == 0) ? wq : (by == 1) ? wk : wv;
        dst = W3 + (size_t)by * 1024 * 1024;
        R = 1024; C = 64; ho = 64 * 1024; r0 = blockIdx.x * 64; c0 = 0;
    }
    const float* s = src + (size_t)h * R * C;
#pragma unroll
    for (int k = 0; k < 16; k++) {
        int idx = tid + k * 256;
        int i = idx >> 6, j = idx & 63;
        tile[i][j] = s[(size_t)(r0 + i) * C + (c0 + j)];
    }
    __syncthreads();
    u16* d = dst + (size_t)h * ho;
#pragma unroll
    for (int k = 0; k < 16; k++) {
        int idx = tid + k * 256;
        int j = idx >> 6, i = idx & 63;
        d[(size_t)(c0 + j) * 1024 + (r0 + i)] = f2bf(tile[i][j]);
    }
}

// ---------------- fused QKV projection GEMM ----------------
// ny<8 -> Q, 8..15 -> K, 16..23 -> V (V epilogue: LDS transpose -> coalesced Vt write).
__global__ __launch_bounds__(256) void proj_kernel(const u16* __restrict__ Xq, const u16* __restrict__ Xkv,
                                                   const u16* __restrict__ W3,
                                                   u16* __restrict__ Qp, u16* __restrict__ Kp,
                                                   u16* __restrict__ Vt) {
    __shared__ __align__(16) u16 As[128 * 32];
    __shared__ __align__(16) u16 Bs[128 * 32];
    __shared__ __align__(16) u16 Ts[128 * 136];  // V transpose staging (only sel==2 uses)
    int tid = threadIdx.x;
    int ny = blockIdx.y;
    int sel = ny >> 3;
    const u16* A  = (sel == 0) ? Xq : Xkv;
    const u16* Bt = W3 + (size_t)sel * 1024 * 1024;
    int m0 = blockIdx.x * 128, n0 = (ny & 7) * 128;
    int w = tid >> 6, lane = tid & 63, quad = lane >> 4, c = lane & 15;
    int mw = (w & 1) * 64, nw = (w >> 1) * 64;
    f32x4 acc[4][4];
#pragma unroll
    for (int i = 0; i < 4; i++)
#pragma unroll
        for (int j = 0; j < 4; j++) acc[i][j] = zero4();

    for (int k0 = 0; k0 < 1024; k0 += 32) {
        __syncthreads();
#pragma unroll
        for (int s = 0; s < 2; s++) {
            int ch = s * 256 + w * 64 + lane;
            int r = ch >> 2, cc = (ch & 3) * 8;
            gl_lds16(&A[(size_t)(m0 + r) * 1024 + k0 + cc],  &As[(s * 256 + w * 64) * 8]);
            gl_lds16(&Bt[(size_t)(n0 + r) * 1024 + k0 + cc], &Bs[(s * 256 + w * 64) * 8]);
        }
        asm volatile("s_waitcnt vmcnt(0)" ::: "memory");
        __syncthreads();
        bf16x8 af[4], bfr[4];
#pragma unroll
        for (int i = 0; i < 4; i++) af[i] = *(const bf16x8*)&As[(mw + i * 16 + c) * 32 + quad * 8];
#pragma unroll
        for (int j = 0; j < 4; j++) bfr[j] = *(const bf16x8*)&Bs[(nw + j * 16 + c) * 32 + quad * 8];
#pragma unroll
        for (int i = 0; i < 4; i++)
#pragma unroll
            for (int j = 0; j < 4; j++) acc[i][j] = MFMA(af[i], bfr[j], acc[i][j]);
    }
    if (sel < 2) {
        u16* C_ = (sel == 0) ? Qp : Kp;
#pragma unroll
        for (int i = 0; i < 4; i++)
#pragma unroll
            for (int r = 0; r < 4; r++) {
                int row = m0 + mw + i * 16 + quad * 4 + r;
#pragma unroll
                for (int j = 0; j < 4; j++)
                    C_[(size_t)row * 1024 + n0 + nw + j * 16 + c] = f2bf(acc[i][j][r]);
            }
    } else {
        // stash tile transposed in LDS: Ts[col_local][row_local]
#pragma unroll
        for (int i = 0; i < 4; i++)
#pragma unroll
            for (int r = 0; r < 4; r++) {
                int rowL = mw + i * 16 + quad * 4 + r;
#pragma unroll
                for (int j = 0; j < 4; j++)
                    Ts[(nw + j * 16 + c) * 136 + rowL] = f2bf(acc[i][j][r]);
            }
        __syncthreads();
        int bb = m0 >> 10, tbase = m0 & 1023;
#pragma unroll
        for (int it = 0; it < 8; it++) {
            int linear = tid + it * 256;
            int colL = linear >> 4, r0 = (linear & 15) * 8;
            int colG = n0 + colL;
            bf16x8 v = *(const bf16x8*)&Ts[colL * 136 + r0];
            *(bf16x8*)&Vt[(((size_t)(bb * 16 + (colG >> 6)) * 64) + (colG & 63)) * 1024 + tbase + r0] = v;
        }
    }
}

// ---------------- output projection GEMM: out = (Pre @ Wot^T) * (1-qmask) ----------------
__global__ __launch_bounds__(256) void gemmo_kernel(const u16* __restrict__ A, const u16* __restrict__ Bt,
                                                    float* __restrict__ Cf, const float* __restrict__ qmask) {
    __shared__ __align__(16) u16 As[128 * 32];
    __shared__ __align__(16) u16 Bs[128 * 32];
    int tid = threadIdx.x;
    int m0 = blockIdx.x * 128, n0 = blockIdx.y * 128;
    int w = tid >> 6, lane = tid & 63, quad = lane >> 4, c = lane & 15;
    int mw = (w & 1) * 64, nw = (w >> 1) * 64;
    f32x4 acc[4][4];
#pragma unroll
    for (int i = 0; i < 4; i++)
#pragma unroll
        for (int j = 0; j < 4; j++) acc[i][j] = zero4();

    for (int k0 = 0; k0 < 1024; k0 += 32) {
        __syncthreads();
#pragma unroll
        for (int s = 0; s < 2; s++) {
            int ch = s * 256 + w * 64 + lane;
            int r = ch >> 2, cc = (ch & 3) * 8;
            gl_lds16(&A[(size_t)(m0 + r) * 1024 + k0 + cc],  &As[(s * 256 + w * 64) * 8]);
            gl_lds16(&Bt[(size_t)(n0 + r) * 1024 + k0 + cc], &Bs[(s * 256 + w * 64) * 8]);
        }
        asm volatile("s_waitcnt vmcnt(0)" ::: "memory");
        __syncthreads();
        bf16x8 af[4], bfr[4];
#pragma unroll
        for (int i = 0; i < 4; i++) af[i] = *(const bf16x8*)&As[(mw + i * 16 + c) * 32 + quad * 8];
#pragma unroll
        for (int j = 0; j < 4; j++) bfr[j] = *(const bf16x8*)&Bs[(nw + j * 16 + c) * 32 + quad * 8];
#pragma unroll
        for (int i = 0; i < 4; i++)
#pragma unroll
            for (int j = 0; j < 4; j++) acc[i][j] = MFMA(af[i], bfr[j], acc[i][j]);
    }
#pragma unroll
    for (int i = 0; i < 4; i++) {
#pragma unroll
        for (int r = 0; r < 4; r++) {
            int row = m0 + mw + i * 16 + quad * 4 + r;
            float scale = 1.0f - qmask[row];
#pragma unroll
            for (int j = 0; j < 4; j++) {
                int col = n0 + nw + j * 16 + c;
                Cf[(size_t)row * 1024 + col] = acc[i][j][r] * scale;
            }
        }
    }
}

// ---------------- flash attention: pair-balanced, double-buffered DMA pipeline ----------------
// grid (8,16,4), 512 thr. Waves 0-3 -> heavy q-block (15-bx); waves 4-7 -> light q-block bx.
// Staged chunks nA = 16-bx (uniform across waves; light waves idle-compute past nB = bx+1).
// K/V staged via global_load_lds, XOR swizzle (unit ^= row&7) on global addr; raw s_barrier
// (no vmcnt drain) + fine s_waitcnt vmcnt(2/1) keeps next chunk's DMA in flight over compute.
__global__ __launch_bounds__(512) void attn_kernel(const u16* __restrict__ Qp, const u16* __restrict__ Kp,
                                                   const u16* __restrict__ Vt, u16* __restrict__ Pre,
                                                   float* __restrict__ marg) {
    __shared__ __align__(16) u16 Ks[2][64 * 64];
    __shared__ __align__(16) u16 Vs[2][64 * 64];
    __shared__ __align__(16) u16 plds[8][16 * 72];
    __shared__ float colbuf[1024];
    int tid = threadIdx.x;
    int bx = blockIdx.x, h = blockIdx.y, b = blockIdx.z;
    int w = tid >> 6, lane = tid & 63, quad = lane >> 4, c = lane & 15;
    int nA = 16 - bx, nB = bx + 1;
    int tmaxb = nA * 64;
    for (int i = tid; i < tmaxb; i += 512) colbuf[i] = 0.f;

    int nq = (w < 4) ? nA : nB;
    int q0 = (w < 4) ? ((15 - bx) * 64 + w * 16) : (bx * 64 + (w - 4) * 16);

    const u16* qrow = Qp + (size_t)(b * 1024 + q0 + c) * 1024 + h * 64;
    bf16x8 aq0 = *(const bf16x8*)(qrow + quad * 8);
    bf16x8 aq1 = *(const bf16x8*)(qrow + 32 + quad * 8);

    const u16* kb = Kp + (size_t)b * 1024 * 1024 + h * 64;
    const u16* vb = Vt + (size_t)(b * 16 + h) * 64 * 1024;
    u16* pl = plds[w];
    const float sc = 0.125f * 1.4426950408889634f;  // kscale * log2(e)

    // staging geometry: tid covers (row = tid>>3, unit = tid&7) of a 64x64 chunk
    int rowS = tid >> 3;
    int lu = (tid & 7) ^ (rowS & 7);       // swizzled logical unit fetched by this lane
    int sw = c & 7;
    int su0 = (quad ^ sw) * 8;             // storage offset of logical unit 'quad'
    int su1 = ((quad ^ 4) ^ sw) * 8;       // storage offset of logical unit 'quad+4'
    u16* ldsK = &Ks[0][0] + w * 512;       // wave's 1KB DMA slice (buf 1 = +4096)
    u16* ldsV = &Vs[0][0] + w * 512;

    f32x4 o[4];
#pragma unroll
    for (int i = 0; i < 4; i++) o[i] = zero4();
    float l[4] = {0.f, 0.f, 0.f, 0.f};
    int qg[4];
#pragma unroll
    for (int r = 0; r < 4; r++) qg[r] = q0 + quad * 4 + r;

    // ---------------- sweep 1: S -> exp -> PV, row sums ----------------
    gl_lds16(kb + (size_t)rowS * 1024 + lu * 8, ldsK);
    gl_lds16(vb + (size_t)rowS * 1024 + lu * 8, ldsV);
    for (int ci = 0; ci < nA; ci++) {
        int bf = ci & 1;
        barrier_nodrain();
        if (ci + 1 < nA) {
            gl_lds16(kb + (size_t)((ci + 1) * 64 + rowS) * 1024 + lu * 8, ldsK + (bf ^ 1) * 4096);
            gl_lds16(vb + (size_t)rowS * 1024 + (ci + 1) * 64 + lu * 8,  ldsV + (bf ^ 1) * 4096);
            asm volatile("s_waitcnt vmcnt(2)" ::: "memory");
        } else {
            asm volatile("s_waitcnt vmcnt(0)" ::: "memory");
        }
        asm volatile("s_barrier" ::: "memory");
        if (ci < nq) {
            const u16* Kb = &Ks[bf][0];
            const u16* Vb = &Vs[bf][0];
            f32x4 s[4];
#pragma unroll
            for (int j = 0; j < 4; j++) {
                const u16* kr = Kb + (j * 16 + c) * 64;
                bf16x8 b0 = *(const bf16x8*)(kr + su0);
                bf16x8 b1 = *(const bf16x8*)(kr + su1);
                s[j] = MFMA(aq0, b0, zero4());
                s[j] = MFMA(aq1, b1, s[j]);
            }
            if (ci < nq - 1) {  // full chunk
#pragma unroll
                for (int j = 0; j < 4; j++)
#pragma unroll
                    for (int r = 0; r < 4; r++) {
                        float e = exp2f(s[j][r] * sc);
                        l[r] += e;
                        pl[(quad * 4 + r) * 72 + j * 16 + c] = f2bf(e);
                    }
            } else {  // diagonal chunk
#pragma unroll
                for (int j = 0; j < 4; j++) {
                    int t = ci * 64 + j * 16 + c;
#pragma unroll
                    for (int r = 0; r < 4; r++) {
                        float e = (t <= qg[r]) ? exp2f(s[j][r] * sc) : 0.f;
                        l[r] += e;
                        pl[(quad * 4 + r) * 72 + j * 16 + c] = f2bf(e);
                    }
                }
            }
            asm volatile("s_waitcnt lgkmcnt(0)" ::: "memory");
            bf16x8 ap0 = *(const bf16x8*)&pl[c * 72 + quad * 8];
            bf16x8 ap1 = *(const bf16x8*)&pl[c * 72 + 32 + quad * 8];
#pragma unroll
            for (int vt = 0; vt < 4; vt++) {
                const u16* vr = Vb + (vt * 16 + c) * 64;
                bf16x8 bv0 = *(const bf16x8*)(vr + su0);
                bf16x8 bv1 = *(const bf16x8*)(vr + su1);
                o[vt] = MFMA(ap0, bv0, o[vt]);
                o[vt] = MFMA(ap1, bv1, o[vt]);
            }
        }
    }

    float invl[4];
#pragma unroll
    for (int r = 0; r < 4; r++) {
        float lr = l[r];
#pragma unroll
        for (int d = 1; d < 16; d <<= 1) lr += __shfl_xor(lr, d);
        invl[r] = 1.0f / lr;
    }
#pragma unroll
    for (int vt = 0; vt < 4; vt++)
#pragma unroll
        for (int r = 0; r < 4; r++) {
            size_t row = (size_t)(b * 1024 + q0 + quad * 4 + r);
            Pre[row * 1024 + h * 64 + vt * 16 + c] = f2bf(o[vt][r] * invl[r]);
        }

    // ---------------- sweep 2: column marginals sum_q att[q,t]*(q+1) ----------------
    float wr[4];
#pragma unroll
    for (int r = 0; r < 4; r++) wr[r] = (float)(qg[r] + 1) * invl[r];
    asm volatile("s_waitcnt vmcnt(0)" ::: "memory");  // drain Pre stores (vmcnt bookkeeping)
    __syncthreads();                                   // colbuf init + buffer reuse safety
    gl_lds16(kb + (size_t)rowS * 1024 + lu * 8, ldsK);
    for (int ci = 0; ci < nA; ci++) {
        int bf = ci & 1;
        barrier_nodrain();
        if (ci + 1 < nA) {
            gl_lds16(kb + (size_t)((ci + 1) * 64 + rowS) * 1024 + lu * 8, ldsK + (bf ^ 1) * 4096);
            asm volatile("s_waitcnt vmcnt(1)" ::: "memory");
        } else {
            asm volatile("s_waitcnt vmcnt(0)" ::: "memory");
        }
        asm volatile("s_barrier" ::: "memory");
        if (ci < nq) {
            const u16* Kb = &Ks[bf][0];
            f32x4 s[4];
#pragma unroll
            for (int j = 0; j < 4; j++) {
                const u16* kr = Kb + (j * 16 + c) * 64;
                bf16x8 b0 = *(const bf16x8*)(kr + su0);
                bf16x8 b1 = *(const bf16x8*)(kr + su1);
                s[j] = MFMA(aq0, b0, zero4());
                s[j] = MFMA(aq1, b1, s[j]);
            }
            float a[4];
            if (ci < nq - 1) {
#pragma unroll
                for (int j = 0; j < 4; j++) {
                    float aj = 0.f;
#pragma unroll
                    for (int r = 0; r < 4; r++) aj += exp2f(s[j][r] * sc) * wr[r];
                    aj += __shfl_xor(aj, 16);
                    aj += __shfl_xor(aj, 32);
                    a[j] = aj;
                }
            } else {
#pragma unroll
                for (int j = 0; j < 4; j++) {
                    int t = ci * 64 + j * 16 + c;
                    float aj = 0.f;
#pragma unroll
                    for (int r = 0; r < 4; r++) aj += (t <= qg[r]) ? exp2f(s[j][r] * sc) * wr[r] : 0.f;
                    aj += __shfl_xor(aj, 16);
                    aj += __shfl_xor(aj, 32);
                    a[j] = aj;
                }
            }
            float v = (quad == 0) ? a[0] : (quad == 1) ? a[1] : (quad == 2) ? a[2] : a[3];
            atomicAdd(&colbuf[ci * 64 + lane], v);
        }
    }
    __syncthreads();
    for (int t = tid; t < tmaxb; t += 512) atomicAdd(&marg[b * 1024 + t], colbuf[t]);
}

// ---------------- entropy: marg (B,1024) -> scaled_entr (B) ----------------
__global__ __launch_bounds__(256) void entropy_kernel(const float* __restrict__ marg, float* __restrict__ out) {
    int b = blockIdx.x, tid = threadIdx.x;
    __shared__ float red[256];
    float s = 0.f;
    for (int t = tid; t < 1024; t += 256) s += marg[b * 1024 + t];
    red[tid] = s; __syncthreads();
    for (int k = 128; k > 0; k >>= 1) { if (tid < k) red[tid] += red[tid + k]; __syncthreads(); }
    float tot = red[0];
    __syncthreads();
    float e = 0.f;
    for (int t = tid; t < 1024; t += 256) {
        float p = marg[b * 1024 + t] / tot;
        if (p > 0.f) e -= p * log2f(p);
    }
    red[tid] = e; __syncthreads();
    for (int k = 128; k > 0; k >>= 1) { if (tid < k) red[tid] += red[tid + k]; __syncthreads(); }
    if (tid == 0) out[b] = red[0] * 0.1f;  // / log2(c=1024)
}

extern "C" void kernel_launch(void* const* d_in, const int* in_sizes, int n_in,
                              void* d_out, int out_size, void* d_ws, size_t ws_size,
                              hipStream_t stream) {
    const float* qinput  = (const float*)d_in[0];
    const float* kvinput = (const float*)d_in[1];
    const float* qmask   = (const float*)d_in[2];
    const float* wq = (const float*)d_in[5];
    const float* wk = (const float*)d_in[6];
    const float* wv = (const float*)d_in[7];
    const float* wo = (const float*)d_in[8];

    char* ws = (char*)d_ws;
    const size_t MB = 1024 * 1024;
    u16* Xq   = (u16*)(ws + 0);        // 8MB, reused as Pre after Q-proj consumed
    u16* Xkv  = (u16*)(ws + 8 * MB);   // 8MB
    u16* W3   = (u16*)(ws + 16 * MB);  // Wqt|Wkt|Wvt contiguous, 2MB each
    u16* Wot  = (u16*)(ws + 22 * MB);
    u16* Qp   = (u16*)(ws + 24 * MB);  // 8MB
    u16* Kp   = (u16*)(ws + 32 * MB);  // 8MB
    u16* Vt   = (u16*)(ws + 40 * MB);  // 8MB (B,H,V,T)
    float* marg = (float*)(ws + 48 * MB);  // 16KB
    u16* Pre = Xq;
    float* out = (float*)d_out;

    cvt2_kernel<<<8192, 256, 0, stream>>>(qinput, kvinput, Xq, Xkv);
    wtrans4_kernel<<<dim3(16, 4, 16), 256, 0, stream>>>(wq, wk, wv, wo, W3, Wot);
    proj_kernel<<<dim3(32, 24), 256, 0, stream>>>(Xq, Xkv, W3, Qp, Kp, Vt);

    hipMemsetAsync(marg, 0, 4096 * sizeof(float), stream);
    attn_kernel<<<dim3(8, 16, 4), 512, 0, stream>>>(Qp, Kp, Vt, Pre, marg);  // Pre overwrites Xq
    entropy_kernel<<<4, 256, 0, stream>>>(marg, out + (size_t)4 * 1024 * 1024);
    gemmo_kernel<<<dim3(32, 8), 256, 0, stream>>>(Pre, Wot, out, qmask);
}